// Round 17
// baseline (103.726 us; speedup 1.0000x reference)
//
#include <hip/hip_runtime.h>

// (B,H,W,C) = (16,512,512,3) float32. 4 warp ops.
// out concat order: 0:(frame1,f01) 1:(frame0,f10) 2:(frame0,ft0) 3:(frame1,ft1)
#define HH 512
#define WW 512
#define NPIX (16 * HH * WW)
#define IMG_DW (HH * WW * 3)     // dwords per image
#define ROWD_G (WW * 3)          // global image row stride in dwords

#define TSX   64                 // output tile width
#define TSY   32                 // output tile height (64x32: apron ratio 2.41x)
#define APRX  12                 // x apron
#define APRY  12                 // y apron
#define LWX   (TSX + 2 * APRX)   // 88: staged region width (px)
#define LWY   (TSY + 2 * APRY)   // 56: staged region height (rows)
#define LSTR  (LWX * 3)          // 264: row stride (16B chunk-aligned: 264%4==0)
#define LDSDW (LWY * LSTR)       // 14784 dwords = 59,136 B -> 2 blocks/CU of 512thr
#define NCHUNK (LDSDW / 4)       // 3696 16B chunks = 7*512 + 112
#define NTHR  512

typedef float fv4 __attribute__((ext_vector_type(4)));
typedef float fv2 __attribute__((ext_vector_type(2)));
typedef fv4 fv4u __attribute__((aligned(4)));
typedef fv2 fv2u __attribute__((aligned(4)));

__device__ __forceinline__ void sample(const float* __restrict__ imgb,
                                       const float* __restrict__ s,
                                       int AX0, int AY0,
                                       float qy, float qx, float* __restrict__ r)
{
    float fy = floorf(qy); fy = fminf(fmaxf(fy, 0.0f), (float)(HH - 2));
    float fx = floorf(qx); fx = fminf(fmaxf(fx, 0.0f), (float)(WW - 2));
    const float ay = fminf(fmaxf(qy - fy, 0.0f), 1.0f);
    const float ax = fminf(fmaxf(qx - fx, 0.0f), 1.0f);
    const int y0 = (int)fy, x0 = (int)fx;
    const int yl = y0 - AY0, xl = x0 - AX0;
    if ((unsigned)yl < (unsigned)(LWY - 1) && (unsigned)xl < (unsigned)(LWX - 1)) {
        // LDS path: AoS rows; 6x ds_read2_b32
        const float* t  = s + yl * LSTR + 3 * xl;
        const float* bo = t + LSTR;
#pragma unroll
        for (int c = 0; c < 3; ++c) {
            const float tl = t[c],  tr = t[c + 3];
            const float bl = bo[c], br = bo[c + 3];
            const float top = tl + ax * (tr - tl);
            const float bot = bl + ax * (br - bl);
            r[c] = top + ay * (bot - top);
        }
    } else {
        // rare global fallback (|flow| beyond apron): exact same math
        const float* t  = imgb + ((size_t)y0 * WW + x0) * 3;
        const float* bo = t + WW * 3;
        const fv4u t4 = *(const fv4u*)t;  const fv2u t2 = *(const fv2u*)(t + 4);
        const fv4u b4 = *(const fv4u*)bo; const fv2u b2 = *(const fv2u*)(bo + 4);
        const float tv[6] = {t4.x, t4.y, t4.z, t4.w, t2.x, t2.y};
        const float bv[6] = {b4.x, b4.y, b4.z, b4.w, b2.x, b2.y};
#pragma unroll
        for (int c = 0; c < 3; ++c) {
            const float top = tv[c] + ax * (tv[c + 3] - tv[c]);
            const float bot = bv[c] + ax * (bv[c + 3] - bv[c]);
            r[c] = top + ay * (bot - top);
        }
    }
}

__global__ __launch_bounds__(NTHR) void warp_t64_kernel(
    const float* __restrict__ frame0, const float* __restrict__ frame1,
    const float* __restrict__ f01, const float* __restrict__ f10,
    const float* __restrict__ ft0, const float* __restrict__ ft1,
    float* __restrict__ out)
{
    __shared__ float lds[LDSDW];   // 59,136 B -> 2 blocks/CU (16 waves, 50%)

    // 4096 blocks; bijective XCD chunking: XCD k gets 512 contiguous units
    // = 4 whole (fg,b) images (3 MB fits 4 MB per-XCD L2); consecutive units
    // walk one image row-by-row so apron overlap stays L2-hot.
    const unsigned bid = blockIdx.x;
    const unsigned v   = (bid & 7u) * 512u + (bid >> 3);

    const unsigned tile  = v & 127u;   // 8 x 16 tiles per image
    const unsigned img_b = v >> 7;     // 0..31
    const int b  = (int)(img_b & 15u);
    const int fg = (int)(img_b >> 4);  // 0: frame0 ops{1,2}, 1: frame1 ops{0,3}

    const int tx = (int)(tile & 7u);
    const int ty = (int)(tile >> 3);
    const int X0 = tx * TSX, Y0 = ty * TSY;
    const int AX0 = X0 - APRX, AY0 = Y0 - APRY;

    const float* img   = fg ? frame1 : frame0;
    const float* flowA = fg ? f01 : f10;
    const float* flowB = fg ? ft1 : ft0;
    const size_t opA   = fg ? 0 : 1;
    const size_t opB   = fg ? 3 : 2;

    const float* imgb = img + (size_t)b * IMG_DW;

    const int tid = (int)threadIdx.x;
    const int lx = (tid & 15) * 4;     // 16 threads x 4 px cover 64 px row
    const int ly = tid >> 4;           // 32 rows
    const int x = X0 + lx, y = Y0 + ly;
    const size_t pixIn = ((size_t)b * HH + y) * WW + x;

    // Flow loads FIRST (oldest in vmcnt queue): the coord math below waits
    // only for these, not for the glds batch issued after.
    const fv4 a0 = __builtin_nontemporal_load((const fv4*)(flowA + pixIn * 2));
    const fv4 a1 = __builtin_nontemporal_load((const fv4*)(flowA + pixIn * 2) + 1);
    const fv4 c0 = __builtin_nontemporal_load((const fv4*)(flowB + pixIn * 2));
    const fv4 c1 = __builtin_nontemporal_load((const fv4*)(flowB + pixIn * 2) + 1);

    // ---- Stage apron region HBM -> LDS via global_load_lds (async, 0 VGPR).
    // 3696 16B chunks; thread tid handles chunk it*512+tid. LDS dest is
    // wave-uniform base + lane*16 (HW contract); LSTR%4==0, rows unpadded so
    // every chunk is pure payload within one region row. Out-of-image apron
    // cells are never read (bilinear clip); source clamp is fault-safety only.
    {
        const unsigned wid = __builtin_amdgcn_readfirstlane((unsigned)tid >> 6);
        int D   = tid * 4;             // LDS dword index of this thread's chunk
        int row = D / LSTR;            // magic-mul, once
        int rd  = D - row * LSTR;
#pragma unroll
        for (int it = 0; it < 8; ++it) {
            if (it < 7 || tid < (NCHUNK - 7 * NTHR)) {  // 112 tail chunks
                const int gy = min(max(AY0 + row, 0), HH - 1);
                int idx = gy * ROWD_G + AX0 * 3 + rd;
                idx = min(max(idx, 0), IMG_DW - 4);
                const float* src = imgb + idx;
                float* dst = (float*)lds + it * (NTHR * 4) + wid * 256;
                __builtin_amdgcn_global_load_lds(
                    (const __attribute__((address_space(1))) void*)src,
                    (__attribute__((address_space(3))) void*)dst, 16, 0, 0);
            }
            // advance D by 2048 dwords: 2048 = 7*264 + 200
            row += 7; rd += 200;
            if (rd >= LSTR) { rd -= LSTR; ++row; }
        }
    }

    // ---- Overlap: per-sample query coords run while glds drain.
    const float flyA[4] = {a0.x, a0.z, a1.x, a1.z};
    const float flxA[4] = {a0.y, a0.w, a1.y, a1.w};
    const float flyB[4] = {c0.x, c0.z, c1.x, c1.z};
    const float flxB[4] = {c0.y, c0.w, c1.y, c1.w};

    __syncthreads();   // drains the glds batch

    float* oA = out + (opA * NPIX + pixIn) * 3;
    float* oB = out + (opB * NPIX + pixIn) * 3;

    // Op A: 4 samples, NT fv4 stores (16B-aligned: pixIn%4==0 -> *3 %12==0).
    {
        float res[12];
#pragma unroll
        for (int p = 0; p < 4; ++p)
            sample(imgb, lds, AX0, AY0, (float)y - flyA[p], (float)(x + p) - flxA[p], res + 3 * p);
        fv4 s0 = {res[0], res[1], res[2],  res[3]};
        fv4 s1 = {res[4], res[5], res[6],  res[7]};
        fv4 s2 = {res[8], res[9], res[10], res[11]};
        __builtin_nontemporal_store(s0, (fv4*)oA);
        __builtin_nontemporal_store(s1, (fv4*)oA + 1);
        __builtin_nontemporal_store(s2, (fv4*)oA + 2);
    }
    // Op B
    {
        float res[12];
#pragma unroll
        for (int p = 0; p < 4; ++p)
            sample(imgb, lds, AX0, AY0, (float)y - flyB[p], (float)(x + p) - flxB[p], res + 3 * p);
        fv4 s0 = {res[0], res[1], res[2],  res[3]};
        fv4 s1 = {res[4], res[5], res[6],  res[7]};
        fv4 s2 = {res[8], res[9], res[10], res[11]};
        __builtin_nontemporal_store(s0, (fv4*)oB);
        __builtin_nontemporal_store(s1, (fv4*)oB + 1);
        __builtin_nontemporal_store(s2, (fv4*)oB + 2);
    }
}

extern "C" void kernel_launch(void* const* d_in, const int* in_sizes, int n_in,
                              void* d_out, int out_size, void* d_ws, size_t ws_size,
                              hipStream_t stream) {
    const float* frame0 = (const float*)d_in[0];
    const float* frame1 = (const float*)d_in[1];
    const float* f01    = (const float*)d_in[2];
    const float* f10    = (const float*)d_in[3];
    const float* ft0    = (const float*)d_in[4];
    const float* ft1    = (const float*)d_in[5];
    float* out = (float*)d_out;

    // 2 frame-groups * 16 b * 128 tiles = 4096 blocks of 512 threads.
    hipLaunchKernelGGL(warp_t64_kernel, dim3(4096), dim3(NTHR), 0, stream,
                       frame0, frame1, f01, f10, ft0, ft1, out);
}

// Round 18
// 91.472 us; speedup vs baseline: 1.1340x; 1.1340x over previous
//
#include <hip/hip_runtime.h>

// (B,H,W,C) = (16,512,512,3) float32. 4 warp ops.
// out concat order: 0:(frame1,f01) 1:(frame0,f10) 2:(frame0,ft0) 3:(frame1,ft1)
#define HH 512
#define WW 512
#define NPIX (16 * HH * WW)
#define IMG_DW (HH * WW * 3)     // dwords per image
#define ROWD_G (WW * 3)          // global image row stride in dwords

#define TSX   32                 // output tile width
#define TSY   32                 // output tile height (32x32: apron ratio 3.06x)
#define APRX  12                 // x apron
#define APRY  12                 // y apron
#define LWX   (TSX + 2 * APRX)   // 56: staged region width (px)
#define LWY   (TSY + 2 * APRY)   // 56: staged region height (rows)
#define LSTR  (LWX * 3)          // 168: row stride (16B chunk-aligned: 168%4==0)
#define LDSDW (LWY * LSTR)       // 9408 dwords = 37,632 B -> 4 blocks/CU of 512thr
#define NCHUNK (LDSDW / 4)       // 2352 16B chunks = 4*512 + 304
#define NTHR  512

typedef float fv4 __attribute__((ext_vector_type(4)));
typedef float fv2 __attribute__((ext_vector_type(2)));
typedef fv4 fv4u __attribute__((aligned(4)));
typedef fv2 fv2u __attribute__((aligned(4)));

__device__ __forceinline__ void sample(const float* __restrict__ imgb,
                                       const float* __restrict__ s,
                                       int AX0, int AY0,
                                       float qy, float qx, float* __restrict__ r)
{
    float fy = floorf(qy); fy = fminf(fmaxf(fy, 0.0f), (float)(HH - 2));
    float fx = floorf(qx); fx = fminf(fmaxf(fx, 0.0f), (float)(WW - 2));
    const float ay = fminf(fmaxf(qy - fy, 0.0f), 1.0f);
    const float ax = fminf(fmaxf(qx - fx, 0.0f), 1.0f);
    const int y0 = (int)fy, x0 = (int)fx;
    const int yl = y0 - AY0, xl = x0 - AX0;
    if ((unsigned)yl < (unsigned)(LWY - 1) && (unsigned)xl < (unsigned)(LWX - 1)) {
        // LDS path: AoS rows; 6x ds_read2_b32 (dword imm offsets <= 171 < 256)
        const float* t  = s + yl * LSTR + 3 * xl;
        const float* bo = t + LSTR;
#pragma unroll
        for (int c = 0; c < 3; ++c) {
            const float tl = t[c],  tr = t[c + 3];
            const float bl = bo[c], br = bo[c + 3];
            const float top = tl + ax * (tr - tl);
            const float bot = bl + ax * (br - bl);
            r[c] = top + ay * (bot - top);
        }
    } else {
        // rare global fallback (|flow| beyond apron): exact same math
        const float* t  = imgb + ((size_t)y0 * WW + x0) * 3;
        const float* bo = t + WW * 3;
        const fv4u t4 = *(const fv4u*)t;  const fv2u t2 = *(const fv2u*)(t + 4);
        const fv4u b4 = *(const fv4u*)bo; const fv2u b2 = *(const fv2u*)(bo + 4);
        const float tv[6] = {t4.x, t4.y, t4.z, t4.w, t2.x, t2.y};
        const float bv[6] = {b4.x, b4.y, b4.z, b4.w, b2.x, b2.y};
#pragma unroll
        for (int c = 0; c < 3; ++c) {
            const float top = tv[c] + ax * (tv[c + 3] - tv[c]);
            const float bot = bv[c] + ax * (bv[c + 3] - bv[c]);
            r[c] = top + ay * (bot - top);
        }
    }
}

__global__ __launch_bounds__(NTHR) void warp_t32_kernel(
    const float* __restrict__ frame0, const float* __restrict__ frame1,
    const float* __restrict__ f01, const float* __restrict__ f10,
    const float* __restrict__ ft0, const float* __restrict__ ft1,
    float* __restrict__ out)
{
    __shared__ float lds[LDSDW];   // 37,632 B -> 4 blocks/CU (32 waves, 100%)

    // 8192 blocks; bijective XCD chunking: XCD k gets 1024 contiguous units
    // = 4 whole (fg,b) images (3 MB fits 4 MB per-XCD L2); consecutive units
    // walk one image row-by-row so apron overlap stays L2-hot.
    const unsigned bid = blockIdx.x;
    const unsigned v   = (bid & 7u) * 1024u + (bid >> 3);

    const unsigned tile  = v & 255u;   // 16 x 16 tiles per image
    const unsigned img_b = v >> 8;     // 0..31
    const int b  = (int)(img_b & 15u);
    const int fg = (int)(img_b >> 4);  // 0: frame0 ops{1,2}, 1: frame1 ops{0,3}

    const int tx = (int)(tile & 15u);
    const int ty = (int)(tile >> 4);
    const int X0 = tx * TSX, Y0 = ty * TSY;
    const int AX0 = X0 - APRX, AY0 = Y0 - APRY;

    const float* img   = fg ? frame1 : frame0;
    const float* flowA = fg ? f01 : f10;
    const float* flowB = fg ? ft1 : ft0;
    const size_t opA   = fg ? 0 : 1;
    const size_t opB   = fg ? 3 : 2;

    const float* imgb = img + (size_t)b * IMG_DW;

    const int tid = (int)threadIdx.x;
    const int lx = (tid & 15) * 2;     // 16 threads x 2 px cover 32 px row
    const int ly = tid >> 4;           // 32 rows
    const int x = X0 + lx, y = Y0 + ly;
    const size_t pixIn = ((size_t)b * HH + y) * WW + x;

    // Flow loads FIRST (oldest in vmcnt queue): the coord math below waits
    // only for these, not for the glds batch issued after.
    const fv4 a = __builtin_nontemporal_load((const fv4*)(flowA + pixIn * 2));
    const fv4 c = __builtin_nontemporal_load((const fv4*)(flowB + pixIn * 2));

    // ---- Stage apron region HBM -> LDS via global_load_lds (async, 0 VGPR).
    // 2352 16B chunks; thread tid handles chunk it*512+tid. LDS dest is
    // wave-uniform base + lane*16 (HW contract); LSTR%4==0, rows unpadded so
    // every chunk is pure payload within one region row. Out-of-image apron
    // cells are never read (bilinear clip); source clamp is fault-safety only.
    {
        const unsigned wid = __builtin_amdgcn_readfirstlane((unsigned)tid >> 6);
        int D   = tid * 4;             // LDS dword index of this thread's chunk
        int row = D / LSTR;            // magic-mul, once
        int rd  = D - row * LSTR;
#pragma unroll
        for (int it = 0; it < 5; ++it) {
            if (it < 4 || tid < (NCHUNK - 4 * NTHR)) {  // 304 tail chunks
                const int gy = min(max(AY0 + row, 0), HH - 1);
                int idx = gy * ROWD_G + AX0 * 3 + rd;
                idx = min(max(idx, 0), IMG_DW - 4);
                const float* src = imgb + idx;
                float* dst = (float*)lds + it * (NTHR * 4) + wid * 256;
                __builtin_amdgcn_global_load_lds(
                    (const __attribute__((address_space(1))) void*)src,
                    (__attribute__((address_space(3))) void*)dst, 16, 0, 0);
            }
            // advance D by 2048 dwords: 2048 = 12*168 + 32
            row += 12; rd += 32;
            if (rd >= LSTR) { rd -= LSTR; ++row; }
        }
    }

    // ---- Overlap: per-sample coordinate math runs while glds drain.
    float qy0 = (float)y - a.x, qx0 = (float)x       - a.y;
    float qy1 = (float)y - a.z, qx1 = (float)(x + 1) - a.w;
    float qy2 = (float)y - c.x, qx2 = (float)x       - c.y;
    float qy3 = (float)y - c.z, qx3 = (float)(x + 1) - c.w;

    __syncthreads();   // drains the glds batch

    float* oA = out + (opA * NPIX + pixIn) * 3;
    float* oB = out + (opB * NPIX + pixIn) * 3;

    // Op A: 2 samples, store immediately (short live-range).
    {
        float res[6];
        sample(imgb, lds, AX0, AY0, qy0, qx0, res);
        sample(imgb, lds, AX0, AY0, qy1, qx1, res + 3);
        fv2 v0s = {res[0], res[1]};
        fv2 v1s = {res[2], res[3]};
        fv2 v2s = {res[4], res[5]};
        __builtin_nontemporal_store(v0s, (fv2*)oA);
        __builtin_nontemporal_store(v1s, (fv2*)oA + 1);
        __builtin_nontemporal_store(v2s, (fv2*)oA + 2);
    }
    // Op B
    {
        float res[6];
        sample(imgb, lds, AX0, AY0, qy2, qx2, res);
        sample(imgb, lds, AX0, AY0, qy3, qx3, res + 3);
        fv2 v0s = {res[0], res[1]};
        fv2 v1s = {res[2], res[3]};
        fv2 v2s = {res[4], res[5]};
        __builtin_nontemporal_store(v0s, (fv2*)oB);
        __builtin_nontemporal_store(v1s, (fv2*)oB + 1);
        __builtin_nontemporal_store(v2s, (fv2*)oB + 2);
    }
}

extern "C" void kernel_launch(void* const* d_in, const int* in_sizes, int n_in,
                              void* d_out, int out_size, void* d_ws, size_t ws_size,
                              hipStream_t stream) {
    const float* frame0 = (const float*)d_in[0];
    const float* frame1 = (const float*)d_in[1];
    const float* f01    = (const float*)d_in[2];
    const float* f10    = (const float*)d_in[3];
    const float* ft0    = (const float*)d_in[4];
    const float* ft1    = (const float*)d_in[5];
    float* out = (float*)d_out;

    // 2 frame-groups * 16 b * 256 tiles = 8192 blocks of 512 threads.
    hipLaunchKernelGGL(warp_t32_kernel, dim3(8192), dim3(NTHR), 0, stream,
                       frame0, frame1, f01, f10, ft0, ft1, out);
}